// Round 3
// baseline (1267.984 us; speedup 1.0000x reference)
//
#include <hip/hip_runtime.h>
#include <hip/hip_bf16.h>
#include <math.h>

// Gen3Dmol_Classify: B=8 N=256 D=768 H=8 HD=96 F=3072 K=128 L=8 V=32 E=1024 C=2
// Round 2: gload_lds GEMM staging, split-K FFN2, fused attention, barrier-free gauss.

#define DEV_INLINE __device__ __forceinline__

typedef __attribute__((ext_vector_type(8))) short short8v;
typedef __attribute__((ext_vector_type(4))) short short4v;
typedef __attribute__((ext_vector_type(4))) float f32x4;

typedef __attribute__((address_space(1))) const unsigned int GLD_SRC;
typedef __attribute__((address_space(3))) unsigned int LDS_DST;

DEV_INLINE void gload16(const unsigned short* g, unsigned short* l) {
  __builtin_amdgcn_global_load_lds((GLD_SRC*)(const void*)g, (LDS_DST*)(void*)l, 16, 0, 0);
}
DEV_INLINE unsigned short f2bf(float f) {
  unsigned u = __float_as_uint(f);
  return (unsigned short)((u + 0x7fffu + ((u >> 16) & 1u)) >> 16);
}
DEV_INLINE float gelu_f(float v) {
  return 0.5f * v * (1.0f + erff(v * 0.70710678118654752f));
}
DEV_INLINE f32x4 zero4() { f32x4 z; z[0]=0.f; z[1]=0.f; z[2]=0.f; z[3]=0.f; return z; }

// ---------------------------------------------------------------------------
// Weight cast + transpose: W[K][N] fp32 -> Wt[N][K] bf16 (per blockIdx.z layer)
// ---------------------------------------------------------------------------
__global__ __launch_bounds__(256) void k_cast_t(
    const float* __restrict__ W, unsigned short* __restrict__ Wt, int K, int N)
{
  __shared__ float s[64][68];
  const int tid = threadIdx.x;
  const size_t lay = (size_t)blockIdx.z * K * N;
  const int k0 = blockIdx.x * 64, n0 = blockIdx.y * 64;
  const int r = tid >> 4, c4 = (tid & 15) << 2;
  #pragma unroll
  for (int i = 0; i < 4; ++i)
    *(float4*)&s[r + i * 16][c4] =
        *(const float4*)(W + lay + (size_t)(k0 + r + i * 16) * N + n0 + c4);
  __syncthreads();
  const int n = tid & 63, kc = (tid >> 6) << 4;
  short8v v0, v1;
  #pragma unroll
  for (int j = 0; j < 8; ++j) v0[j] = (short)f2bf(s[kc + j][n]);
  #pragma unroll
  for (int j = 0; j < 8; ++j) v1[j] = (short)f2bf(s[kc + 8 + j][n]);
  unsigned short* dst = Wt + lay + (size_t)(n0 + n) * K + k0 + kc;
  *(short8v*)dst = v0;
  *(short8v*)(dst + 8) = v1;
}

// ---------------------------------------------------------------------------
// MFMA GEMM: C[2048][N] = A[2048][Kfull](bf16) @ Bt[N][Kfull]^T + bias
// BM=128, BK=64, BN in {64,128}. 4 waves (2x2). global_load_lds staging with
// pre-swizzled source (linear LDS dest, XOR-swizzled reads).
// EPI: 0 bias->bf16 | 1 bias+gelu->bf16 | 2 bias+res->fp32 | 3 raw fp32 split-K
// For EPI=3: gridDim.z=2, part z covers K [z*Klen, (z+1)*Klen), out z? C1 : C0,
// bias added only by part 0.
// ---------------------------------------------------------------------------
template<int BN, int EPI>
__global__ __launch_bounds__(256) void k_gemm(
    const unsigned short* __restrict__ A, const unsigned short* __restrict__ Bt,
    const float* __restrict__ bias, const float* __restrict__ res,
    void* __restrict__ C0, void* __restrict__ C1, int N, int Kfull, int Klen)
{
  constexpr int NB = BN / 32;
  __shared__ __align__(16) unsigned short As[128 * 64];
  __shared__ __align__(16) unsigned short Bs[BN * 64];
  const int tid = threadIdx.x;
  const int l = tid & 63;
  const int w = tid >> 6, wr = w >> 1, wc = w & 1;
  const int row0 = blockIdx.x * 128, col0 = blockIdx.y * BN;
  const int z = blockIdx.z;
  const int Koff = z * Klen;
  const int NT = Klen >> 6;

  // staging: lane covers LDS row chunkrow0 + (l>>3), 16B slot (l&7);
  // source chunk pre-permuted by (l&7)^(l>>3) so LDS image is linear-with-
  // inverse-swizzle => swizzled reads below recover the logical data.
  const int lr = l >> 3;
  const int lc = ((l & 7) ^ lr) << 3;    // element offset of 16B chunk
  const unsigned short* gA[4];
  #pragma unroll
  for (int i = 0; i < 4; ++i)
    gA[i] = A + (size_t)(row0 + w * 32 + i * 8 + lr) * Kfull + Koff + lc;
  const unsigned short* gB[NB];
  #pragma unroll
  for (int i = 0; i < NB; ++i)
    gB[i] = Bt + (size_t)(col0 + w * (8 * NB) + i * 8 + lr) * Kfull + Koff + lc;

  f32x4 acc[4][NB];
  #pragma unroll
  for (int mi = 0; mi < 4; ++mi)
    #pragma unroll
    for (int ni = 0; ni < NB; ++ni) acc[mi][ni] = zero4();

  for (int kt = 0; kt < NT; ++kt) {
    #pragma unroll
    for (int i = 0; i < 4; ++i)
      gload16(gA[i] + kt * 64, &As[(w * 32 + i * 8) * 64]);
    #pragma unroll
    for (int i = 0; i < NB; ++i)
      gload16(gB[i] + kt * 64, &Bs[(w * (8 * NB) + i * 8) * 64]);
    __syncthreads();   // drains vmcnt -> staged data visible
    #pragma unroll
    for (int kk = 0; kk < 2; ++kk) {
      short8v af[4], bf_[NB];
      #pragma unroll
      for (int mi = 0; mi < 4; ++mi) {
        int rw = wr * 64 + mi * 16 + (l & 15);
        int kb = (kk * 64 + ((l >> 4) << 4)) ^ ((rw & 7) << 4);
        af[mi] = *(const short8v*)&As[rw * 64 + (kb >> 1)];
      }
      #pragma unroll
      for (int ni = 0; ni < NB; ++ni) {
        int rw = wc * (BN / 2) + ni * 16 + (l & 15);
        int kb = (kk * 64 + ((l >> 4) << 4)) ^ ((rw & 7) << 4);
        bf_[ni] = *(const short8v*)&Bs[rw * 64 + (kb >> 1)];
      }
      #pragma unroll
      for (int mi = 0; mi < 4; ++mi)
        #pragma unroll
        for (int ni = 0; ni < NB; ++ni)
          acc[mi][ni] = __builtin_amdgcn_mfma_f32_16x16x32_bf16(
              af[mi], bf_[ni], acc[mi][ni], 0, 0, 0);
    }
    __syncthreads();   // reads done before next overwrite
  }

  const int cl = l & 15, rg = (l >> 4) << 2;
  void* Cv = (EPI == 3 && z) ? C1 : C0;
  float bv[NB];
  #pragma unroll
  for (int ni = 0; ni < NB; ++ni)
    bv[ni] = (EPI == 3 && z) ? 0.f : bias[col0 + wc * (BN / 2) + ni * 16 + cl];
  #pragma unroll
  for (int mi = 0; mi < 4; ++mi) {
    #pragma unroll
    for (int r = 0; r < 4; ++r) {
      size_t rowg = row0 + wr * 64 + mi * 16 + rg + r;
      #pragma unroll
      for (int ni = 0; ni < NB; ++ni) {
        size_t off = rowg * N + col0 + wc * (BN / 2) + ni * 16 + cl;
        float v = acc[mi][ni][r] + bv[ni];
        if (EPI == 0) ((unsigned short*)Cv)[off] = f2bf(v);
        if (EPI == 1) ((unsigned short*)Cv)[off] = f2bf(gelu_f(v));
        if (EPI == 2) ((float*)Cv)[off] = v + res[off];
        if (EPI == 3) ((float*)Cv)[off] = v;
      }
    }
  }
}

// ---------------------------------------------------------------------------
// Gaussian edge features + MLP via MFMA. 64 positions/block, per-wave t1
// slice (no mid-kernel barriers).
// ---------------------------------------------------------------------------
__global__ __launch_bounds__(256) void k_gauss(
    const float* __restrict__ dist, const int* __restrict__ edge,
    const float* __restrict__ gmul, const float* __restrict__ gbias,
    const float* __restrict__ gmeans, const float* __restrict__ gstds,
    const unsigned short* __restrict__ gp1wt, const float* __restrict__ gp1b,
    const float* __restrict__ gp2w, const float* __restrict__ gp2b,
    float* __restrict__ bias_out)
{
  __shared__ float mean_s[128], inv_s[128], coef_s[128], b1s[128];
  __shared__ float b2s[8];
  __shared__ __align__(16) unsigned short w2t[16 * 136];
  __shared__ __align__(16) unsigned short t1[4][2048];  // per-wave 16x128 bf16
  const int tid = threadIdx.x, l = tid & 63, w = tid >> 6;
  const int pos0 = blockIdx.x * 64;

  if (tid < 128) {
    float sd = fabsf(gstds[tid]) + 1e-5f;
    inv_s[tid] = 1.0f / sd;
    coef_s[tid] = 0.39894250f / sd;
    mean_s[tid] = gmeans[tid];
    b1s[tid] = gp1b[tid];
  }
  if (tid < 8) b2s[tid] = gp2b[tid];
  for (int i = tid; i < 2048; i += 256) {
    int hh = i & 15, k = i >> 4;
    w2t[hh * 136 + k] = (hh < 8) ? f2bf(gp2w[k * 8 + hh]) : (unsigned short)0;
  }
  __syncthreads();   // the only barrier

  // per-lane y (4x redundant across lane-groups, removes ys stage)
  const int p = pos0 + w * 16 + (l & 15);
  const int et = edge[p];
  const float y = gmul[et] * dist[p] + gbias[et];

  // phase A: gaussians straight into A-fragments
  short8v ga[4];
  #pragma unroll
  for (int ks = 0; ks < 4; ++ks) {
    #pragma unroll
    for (int j = 0; j < 8; ++j) {
      int k = ks * 32 + ((l >> 4) << 3) + j;
      float z = (y - mean_s[k]) * inv_s[k];
      ga[ks][j] = (short)f2bf(__expf(-0.5f * z * z) * coef_s[k]);
    }
  }
  // phase B: t = g @ gp1w (B-frags from L2-hot gp1wt)
  f32x4 acc[8];
  #pragma unroll
  for (int n = 0; n < 8; ++n) {
    acc[n] = zero4();
    const unsigned short* bp = gp1wt + (size_t)(n * 16 + (l & 15)) * 128 + ((l >> 4) << 3);
    #pragma unroll
    for (int ks = 0; ks < 4; ++ks)
      acc[n] = __builtin_amdgcn_mfma_f32_16x16x32_bf16(
          ga[ks], *(const short8v*)(bp + ks * 32), acc[n], 0, 0, 0);
  }
  // gelu -> per-wave t1 (windowed swizzle: conflict-free scalar writes)
  unsigned short* tw = t1[w];
  {
    const int rb = (l >> 4) << 2;
    #pragma unroll
    for (int n = 0; n < 8; ++n) {
      int col2 = (n * 16 + (l & 15)) * 2;
      float bb = b1s[n * 16 + (l & 15)];
      #pragma unroll
      for (int r = 0; r < 4; ++r) {
        int row = rb + r;
        int swz = ((row & 3) << 4) ^ ((row >> 2) << 5);
        tw[(row * 256 + (col2 ^ swz)) >> 1] = f2bf(gelu_f(acc[n][r] + bb));
      }
    }
  }
  // phase C: pb = t1 @ gp2w (same-wave LDS dep, no barrier)
  f32x4 o4 = zero4();
  {
    const int row = l & 15;
    const int swz = ((row & 3) << 4) ^ ((row >> 2) << 5);
    #pragma unroll
    for (int ks = 0; ks < 4; ++ks) {
      short8v af = *(const short8v*)&tw[(row * 256 + ((ks * 64 + ((l >> 4) << 4)) ^ swz)) >> 1];
      short8v bf_ = *(const short8v*)&w2t[(l & 15) * 136 + ks * 32 + ((l >> 4) << 3)];
      o4 = __builtin_amdgcn_mfma_f32_16x16x32_bf16(af, bf_, o4, 0, 0, 0);
    }
  }
  const int hh = l & 15;
  if (hh < 8) {
    int b = pos0 >> 16;
    int ij = (pos0 & 65535) + w * 16 + ((l >> 4) << 2);
    float4 vv;
    vv.x = o4[0] + b2s[hh]; vv.y = o4[1] + b2s[hh];
    vv.z = o4[2] + b2s[hh]; vv.w = o4[3] + b2s[hh];
    *(float4*)(bias_out + ((size_t)((b << 3) + hh) << 16) + ij) = vv;
  }
}

// ---------------------------------------------------------------------------
// Embedding gather + LayerNorm -> fp32 x
// ---------------------------------------------------------------------------
__global__ __launch_bounds__(256) void k_embed_ln(
    const float* __restrict__ emb, const int* __restrict__ tokens,
    const float* __restrict__ g, const float* __restrict__ bp,
    float* __restrict__ out)
{
  __shared__ float red[4], red2[4];
  const int t = threadIdx.x;
  const int row = blockIdx.x;
  const float* xr = emb + (size_t)tokens[row] * 768;
  float v0 = xr[t], v1 = xr[t + 256], v2 = xr[t + 512];
  float s = v0 + v1 + v2;
  #pragma unroll
  for (int o = 32; o; o >>= 1) s += __shfl_down(s, o);
  if ((t & 63) == 0) red[t >> 6] = s;
  __syncthreads();
  float mean = (red[0] + red[1] + red[2] + red[3]) * (1.0f / 768.0f);
  float d0 = v0 - mean, d1 = v1 - mean, d2 = v2 - mean;
  float q = d0 * d0 + d1 * d1 + d2 * d2;
  #pragma unroll
  for (int o = 32; o; o >>= 1) q += __shfl_down(q, o);
  if ((t & 63) == 0) red2[t >> 6] = q;
  __syncthreads();
  float rstd = rsqrtf((red2[0] + red2[1] + red2[2] + red2[3]) * (1.0f / 768.0f) + 1e-3f);
  float* outr = out + (size_t)row * 768;
  outr[t]       = d0 * rstd * g[t]       + bp[t];
  outr[t + 256] = d1 * rstd * g[t + 256] + bp[t + 256];
  outr[t + 512] = d2 * rstd * g[t + 512] + bp[t + 512];
}

// LayerNorm fp32 -> bf16 h
__global__ __launch_bounds__(256) void k_ln_bf(
    const float* __restrict__ in, const float* __restrict__ g,
    const float* __restrict__ bp, unsigned short* __restrict__ out)
{
  __shared__ float red[4], red2[4];
  const int t = threadIdx.x;
  const size_t base = (size_t)blockIdx.x * 768;
  const float* xr = in + base;
  float v0 = xr[t], v1 = xr[t + 256], v2 = xr[t + 512];
  float s = v0 + v1 + v2;
  #pragma unroll
  for (int o = 32; o; o >>= 1) s += __shfl_down(s, o);
  if ((t & 63) == 0) red[t >> 6] = s;
  __syncthreads();
  float mean = (red[0] + red[1] + red[2] + red[3]) * (1.0f / 768.0f);
  float d0 = v0 - mean, d1 = v1 - mean, d2 = v2 - mean;
  float q = d0 * d0 + d1 * d1 + d2 * d2;
  #pragma unroll
  for (int o = 32; o; o >>= 1) q += __shfl_down(q, o);
  if ((t & 63) == 0) red2[t >> 6] = q;
  __syncthreads();
  float rstd = rsqrtf((red2[0] + red2[1] + red2[2] + red2[3]) * (1.0f / 768.0f) + 1e-3f);
  unsigned short* outr = out + base;
  outr[t]       = f2bf(d0 * rstd * g[t]       + bp[t]);
  outr[t + 256] = f2bf(d1 * rstd * g[t + 256] + bp[t + 256]);
  outr[t + 512] = f2bf(d2 * rstd * g[t + 512] + bp[t + 512]);
}

// ---------------------------------------------------------------------------
// k_fuse: x = p0 + p1 + x (split-K combine + residual); optional LN -> h bf16
// ---------------------------------------------------------------------------
template<int DO_LN>
__global__ __launch_bounds__(256) void k_fuse(
    const float* __restrict__ p0, const float* __restrict__ p1,
    const float* __restrict__ g, const float* __restrict__ bp,
    float* __restrict__ x, unsigned short* __restrict__ h)
{
  __shared__ float red[4], red2[4];
  const int t = threadIdx.x;
  const size_t base = (size_t)blockIdx.x * 768;
  float v0 = p0[base + t]       + p1[base + t]       + x[base + t];
  float v1 = p0[base + t + 256] + p1[base + t + 256] + x[base + t + 256];
  float v2 = p0[base + t + 512] + p1[base + t + 512] + x[base + t + 512];
  x[base + t]       = v0;
  x[base + t + 256] = v1;
  x[base + t + 512] = v2;
  if (DO_LN) {
    float s = v0 + v1 + v2;
    #pragma unroll
    for (int o = 32; o; o >>= 1) s += __shfl_down(s, o);
    if ((t & 63) == 0) red[t >> 6] = s;
    __syncthreads();
    float mean = (red[0] + red[1] + red[2] + red[3]) * (1.0f / 768.0f);
    float d0 = v0 - mean, d1 = v1 - mean, d2 = v2 - mean;
    float q = d0 * d0 + d1 * d1 + d2 * d2;
    #pragma unroll
    for (int o = 32; o; o >>= 1) q += __shfl_down(q, o);
    if ((t & 63) == 0) red2[t >> 6] = q;
    __syncthreads();
    float rstd = rsqrtf((red2[0] + red2[1] + red2[2] + red2[3]) * (1.0f / 768.0f) + 1e-3f);
    h[base + t]       = f2bf(d0 * rstd * g[t]       + bp[t]);
    h[base + t + 256] = f2bf(d1 * rstd * g[t + 256] + bp[t + 256]);
    h[base + t + 512] = f2bf(d2 * rstd * g[t + 512] + bp[t + 512]);
  }
}

// ---------------------------------------------------------------------------
// V transpose: P[b][tok][h*96+d] -> Vt[bh][d][tok]  (bf16)
// ---------------------------------------------------------------------------
__global__ __launch_bounds__(256) void k_transV(
    const unsigned short* __restrict__ P, unsigned short* __restrict__ Vt)
{
  __shared__ unsigned short s[64 * 100];
  const int tid = threadIdx.x;
  const int i0 = blockIdx.x * 64, bh = blockIdx.y, b = bh >> 3, h = bh & 7;
  const unsigned short* Pb = P + ((size_t)b * 256 + i0) * 768 + h * 96;
  #pragma unroll
  for (int i = 0; i < 6; ++i) {
    int o = (tid + i * 256) * 8;
    int row = o / 192, c = o - row * 192;
    *(short4v*)&s[row * 100 + (c >> 1)] =
        *(const short4v*)(Pb + (size_t)row * 768 + (c >> 1));
  }
  __syncthreads();
  #pragma unroll
  for (int i = 0; i < 3; ++i) {
    int u = tid + i * 256;
    int d = u >> 3, tk = (u & 7) << 3;
    short8v v;
    #pragma unroll
    for (int j = 0; j < 8; ++j) v[j] = (short)s[(tk + j) * 100 + d];
    *(short8v*)(Vt + ((size_t)bh * 96 + d) * 256 + i0 + tk) = v;
  }
}

// ---------------------------------------------------------------------------
// Fused attention: probs = softmax(scale*Q.K^T + bias); O = probs @ V.
// K/V fragments read directly from L2-hot global; probs in per-wave LDS.
// grid (4 i-tiles, 64 bh), 4 waves x 16 q-rows, zero barriers.
// ---------------------------------------------------------------------------
__global__ __launch_bounds__(256) void k_attn(
    const unsigned short* __restrict__ P, const unsigned short* __restrict__ Vt,
    const float* __restrict__ bias, unsigned short* __restrict__ O)
{
  __shared__ __align__(16) unsigned short pl[4][4096];  // per-wave 16x256 bf16
  const int tid = threadIdx.x, l = tid & 63, w = tid >> 6;
  const int i0 = blockIdx.x << 6, bh = blockIdx.y, b = bh >> 3, hh = bh & 7;
  const unsigned short* Pb = P + (size_t)b * 196608 + hh * 96;

  short8v aq[3];
  const int rq = i0 + w * 16 + (l & 15);
  #pragma unroll
  for (int ks = 0; ks < 3; ++ks)
    aq[ks] = *(const short8v*)(Pb + (size_t)rq * 768 + ks * 32 + ((l >> 4) << 3));

  f32x4 acc[16];
  #pragma unroll
  for (int n = 0; n < 16; ++n) {
    acc[n] = zero4();
    const unsigned short* kp = Pb + (size_t)(n * 16 + (l & 15)) * 768 + ((l >> 4) << 3);
    #pragma unroll
    for (int ks = 0; ks < 3; ++ks)
      acc[n] = __builtin_amdgcn_mfma_f32_16x16x32_bf16(
          aq[ks], *(const short8v*)(kp + ks * 32), acc[n], 0, 0, 0);
  }

  const float scale = 0.10206207261596577f;  // 1/sqrt(96)
  float inv[4];
  unsigned short* plw = pl[w];
  const size_t brow = ((size_t)bh * 256 + i0 + w * 16 + ((l >> 4) << 2)) * 256 + (l & 15);
  #pragma unroll
  for (int r = 0; r < 4; ++r) {
    const float* bptr = bias + brow + (size_t)r * 256;
    float m = -1e30f;
    #pragma unroll
    for (int n = 0; n < 16; ++n) {
      float v = acc[n][r] * scale + bptr[n * 16];
      acc[n][r] = v;
      m = fmaxf(m, v);
    }
    m = fmaxf(m, __shfl_xor(m, 1)); m = fmaxf(m, __shfl_xor(m, 2));
    m = fmaxf(m, __shfl_xor(m, 4)); m = fmaxf(m, __shfl_xor(m, 8));
    const int rowL = ((l >> 4) << 2) + r;
    const int swz = ((rowL & 3) << 4) ^ ((rowL >> 2) << 5);
    const int cb = (l & 15) << 1;
    float s = 0.f;
    #pragma unroll
    for (int n = 0; n < 16; ++n) {
      float e = __expf(acc[n][r] - m);
      s += e;
      plw[(rowL * 512 + ((cb + (n << 5)) ^ swz)) >> 1] = f2bf(e);
    }
    s += __shfl_xor(s, 1); s += __shfl_xor(s, 2);
    s += __shfl_xor(s, 4); s += __shfl_xor(s, 8);
    inv[r] = 1.0f / s;
  }

  // PV: A-frags from per-wave LDS (same-wave dep, compiler lgkmcnt), B from Vt.
  const int rowA = l & 15;
  const int swzA = ((rowA & 3) << 4) ^ ((rowA >> 2) << 5);
  short8v pa[8];
  #pragma unroll
  for (int ks = 0; ks < 8; ++ks)
    pa[ks] = *(const short8v*)&plw[(rowA * 512 + ((ks * 64 + ((l >> 4) << 4)) ^ swzA)) >> 1];

  unsigned short* Ob = O + ((size_t)b * 256 + i0 + w * 16 + ((l >> 4) << 2)) * 768
                       + hh * 96 + (l & 15);
  #pragma unroll
  for (int n = 0; n < 6; ++n) {
    f32x4 a2 = zero4();
    const unsigned short* vb = Vt + ((size_t)bh * 96 + n * 16 + (l & 15)) * 256 + ((l >> 4) << 3);
    #pragma unroll
    for (int ks = 0; ks < 8; ++ks)
      a2 = __builtin_amdgcn_mfma_f32_16x16x32_bf16(
          pa[ks], *(const short8v*)(vb + ks * 32), a2, 0, 0, 0);
    #pragma unroll
    for (int r = 0; r < 4; ++r)
      Ob[(size_t)r * 768 + n * 16] = f2bf(a2[r] * inv[r]);
  }
}

// ---------------------------------------------------------------------------
// Final LN (row 0 of each batch) + classifier head -> out (8,2), fp32
// ---------------------------------------------------------------------------
__global__ __launch_bounds__(256) void k_cls(
    const float* __restrict__ x, const float* __restrict__ fg,
    const float* __restrict__ fb, const float* __restrict__ w1,
    const float* __restrict__ b1, const float* __restrict__ w2,
    const float* __restrict__ b2, float* __restrict__ out)
{
  __shared__ float ln[768];
  __shared__ float t1[768];
  __shared__ float red[8];
  __shared__ float r2[8];
  const int t = threadIdx.x;
  const int b = blockIdx.x;
  const float* xr = x + (size_t)b * 256 * 768;
  float v0 = xr[t], v1 = xr[t + 256], v2 = xr[t + 512];
  float s = v0 + v1 + v2;
  #pragma unroll
  for (int o = 32; o; o >>= 1) s += __shfl_down(s, o);
  if ((t & 63) == 0) red[t >> 6] = s;
  __syncthreads();
  float mean = (red[0] + red[1] + red[2] + red[3]) * (1.0f / 768.0f);
  float d0 = v0 - mean, d1 = v1 - mean, d2 = v2 - mean;
  float q = d0 * d0 + d1 * d1 + d2 * d2;
  #pragma unroll
  for (int o = 32; o; o >>= 1) q += __shfl_down(q, o);
  if ((t & 63) == 0) red[4 + (t >> 6)] = q;
  __syncthreads();
  float rstd = rsqrtf((red[4] + red[5] + red[6] + red[7]) * (1.0f / 768.0f) + 1e-3f);
  ln[t]       = d0 * rstd * fg[t]       + fb[t];
  ln[t + 256] = d1 * rstd * fg[t + 256] + fb[t + 256];
  ln[t + 512] = d2 * rstd * fg[t + 512] + fb[t + 512];
  __syncthreads();
  float a0 = b1[t], a1 = b1[t + 256], a2 = b1[t + 512];
  for (int d = 0; d < 768; ++d) {
    float lv = ln[d];
    a0 = fmaf(lv, w1[d * 768 + t], a0);
    a1 = fmaf(lv, w1[d * 768 + t + 256], a1);
    a2 = fmaf(lv, w1[d * 768 + t + 512], a2);
  }
  t1[t]       = gelu_f(a0);
  t1[t + 256] = gelu_f(a1);
  t1[t + 512] = gelu_f(a2);
  __syncthreads();
  float p0 = 0.f, p1 = 0.f;
  #pragma unroll
  for (int oo = 0; oo < 3; ++oo) {
    int d = t + oo * 256;
    p0 = fmaf(t1[d], w2[d * 2], p0);
    p1 = fmaf(t1[d], w2[d * 2 + 1], p1);
  }
  #pragma unroll
  for (int o = 32; o; o >>= 1) {
    p0 += __shfl_down(p0, o);
    p1 += __shfl_down(p1, o);
  }
  if ((t & 63) == 0) { r2[t >> 6] = p0; r2[4 + (t >> 6)] = p1; }
  __syncthreads();
  if (t == 0) {
    out[b * 2]     = r2[0] + r2[1] + r2[2] + r2[3] + b2[0];
    out[b * 2 + 1] = r2[4] + r2[5] + r2[6] + r2[7] + b2[1];
  }
}

// ---------------------------------------------------------------------------
extern "C" void kernel_launch(void* const* d_in, const int* in_sizes, int n_in,
                              void* d_out, int out_size, void* d_ws, size_t ws_size,
                              hipStream_t stream)
{
  const float* dist    = (const float*)d_in[0];
  const float* tok_emb = (const float*)d_in[1];
  const float* gmeans  = (const float*)d_in[2];
  const float* gstds   = (const float*)d_in[3];
  const float* gmul    = (const float*)d_in[4];
  const float* gbias   = (const float*)d_in[5];
  const float* gp1w    = (const float*)d_in[6];
  const float* gp1b    = (const float*)d_in[7];
  const float* gp2w    = (const float*)d_in[8];
  const float* gp2b    = (const float*)d_in[9];
  const float* embg    = (const float*)d_in[10];
  const float* embb    = (const float*)d_in[11];
  const float* Wq      = (const float*)d_in[12];
  const float* bq      = (const float*)d_in[13];
  const float* Wo      = (const float*)d_in[14];
  const float* bo      = (const float*)d_in[15];
  const float* ln1g    = (const float*)d_in[16];
  const float* ln1b    = (const float*)d_in[17];
  const float* W1      = (const float*)d_in[18];
  const float* b1      = (const float*)d_in[19];
  const float* W2      = (const float*)d_in[20];
  const float* b2      = (const float*)d_in[21];
  const float* ln2g    = (const float*)d_in[22];
  const float* ln2b    = (const float*)d_in[23];
  const float* fing    = (const float*)d_in[24];
  const float* finb    = (const float*)d_in[25];
  const float* cw1     = (const float*)d_in[26];
  const float* cb1     = (const float*)d_in[27];
  const float* cw2     = (const float*)d_in[28];
  const float* cb2     = (const float*)d_in[29];
  const int*   tokens  = (const int*)d_in[30];
  const int*   edge    = (const int*)d_in[31];

  // workspace layout
  float* ws   = (float*)d_ws;
  float* bias = ws;                        // 4,194,304 f32
  float* x    = bias + 4194304;            // 1,572,864 f32
  float* p0   = x + 1572864;               // 1,572,864 f32
  float* p1   = p0 + 1572864;              // 1,572,864 f32
  unsigned short* hO  = (unsigned short*)(p1 + 1572864);  // 1,572,864 bf16
  unsigned short* P   = hO + 1572864;                     // 1,572,864 bf16
  unsigned short* Vt  = P + 1572864;                      // 1,572,864 bf16
  unsigned short* f1  = Vt + 1572864;                     // 6,291,456 bf16
  unsigned short* Wqt = f1 + 6291456;                     // 4,718,592 bf16
  unsigned short* Wot = Wqt + 4718592;                    // 4,718,592 bf16
  unsigned short* W1t = Wot + 4718592;                    // 18,874,368 bf16
  unsigned short* W2t = W1t + 18874368;                   // 18,874,368 bf16
  unsigned short* g1t = W2t + 18874368;                   // 16,384 bf16
  // total ~152 MiB

  k_cast_t<<<dim3(12, 12, 8), 256, 0, stream>>>(Wq, Wqt, 768, 768);
  k_cast_t<<<dim3(12, 12, 8), 256, 0, stream>>>(Wo, Wot, 768, 768);
  k_cast_t<<<dim3(12, 48, 8), 256, 0, stream>>>(W1, W1t, 768, 3072);
  k_cast_t<<<dim3(48, 12, 8), 256, 0, stream>>>(W2, W2t, 3072, 768);
  k_cast_t<<<dim3(2, 2, 1), 256, 0, stream>>>(gp1w, g1t, 128, 128);

  k_gauss<<<8192, 256, 0, stream>>>(dist, edge, gmul, gbias, gmeans, gstds,
                                    g1t, gp1b, gp2w, gp2b, bias);
  k_embed_ln<<<2048, 256, 0, stream>>>(tok_emb, tokens, embg, embb, x);
  k_ln_bf<<<2048, 256, 0, stream>>>(x, ln1g, ln1b, hO);

  for (int l = 0; l < 8; ++l) {
    k_gemm<64, 0><<<dim3(16, 12, 1), 256, 0, stream>>>(
        hO, Wqt + (size_t)l * 589824, bq + l * 768, nullptr, P, nullptr, 768, 768, 768);
    k_transV<<<dim3(4, 64), 256, 0, stream>>>(P, Vt);
    k_attn<<<dim3(4, 64), 256, 0, stream>>>(P, Vt, bias, hO);
    k_gemm<64, 2><<<dim3(16, 12, 1), 256, 0, stream>>>(
        hO, Wot + (size_t)l * 589824, bo + l * 768, x, x, nullptr, 768, 768, 768);
    k_ln_bf<<<2048, 256, 0, stream>>>(x, ln2g + l * 768, ln2b + l * 768, hO);
    k_gemm<128, 1><<<dim3(16, 24, 1), 256, 0, stream>>>(
        hO, W1t + (size_t)l * 2359296, b1 + l * 3072, nullptr, f1, nullptr, 3072, 768, 768);
    k_gemm<64, 3><<<dim3(16, 12, 2), 256, 0, stream>>>(
        f1, W2t + (size_t)l * 2359296, b2 + l * 768, nullptr, p0, p1, 768, 3072, 1536);
    if (l < 7)
      k_fuse<1><<<2048, 256, 0, stream>>>(p0, p1, ln1g + (l + 1) * 768,
                                          ln1b + (l + 1) * 768, x, hO);
    else
      k_fuse<0><<<2048, 256, 0, stream>>>(p0, p1, nullptr, nullptr, x, hO);
  }
  k_cls<<<8, 256, 0, stream>>>(x, fing, finb, cw1, cb1, cw2, cb2, (float*)d_out);
}

// Round 4
// 1237.840 us; speedup vs baseline: 1.0244x; 1.0244x over previous
//
#include <hip/hip_runtime.h>
#include <hip/hip_bf16.h>
#include <math.h>

// Gen3Dmol_Classify: B=8 N=256 D=768 H=8 HD=96 F=3072 K=128 L=8 V=32 E=1024 C=2
// Round 4: double-buffered gload_lds GEMM (m97 structure), tanh-gelu gauss,
// Wo split-K + fuse-LN.

#define DEV_INLINE __device__ __forceinline__

typedef __attribute__((ext_vector_type(8))) short short8v;
typedef __attribute__((ext_vector_type(4))) short short4v;
typedef __attribute__((ext_vector_type(4))) float f32x4;

typedef __attribute__((address_space(1))) const unsigned int GLD_SRC;
typedef __attribute__((address_space(3))) unsigned int LDS_DST;

DEV_INLINE void gload16(const unsigned short* g, unsigned short* l) {
  __builtin_amdgcn_global_load_lds((GLD_SRC*)(const void*)g, (LDS_DST*)(void*)l, 16, 0, 0);
}
DEV_INLINE unsigned short f2bf(float f) {          // RNE, manual (proven numerics)
  unsigned u = __float_as_uint(f);
  return (unsigned short)((u + 0x7fffu + ((u >> 16) & 1u)) >> 16);
}
DEV_INLINE unsigned short f2bf_hw(float f) {       // HW cvt (hot path in k_gauss)
  __hip_bfloat16 h = __float2bfloat16(f);
  unsigned short u; __builtin_memcpy(&u, &h, 2); return u;
}
DEV_INLINE float gelu_f(float v) {                 // exact (residual-path users)
  return 0.5f * v * (1.0f + erff(v * 0.70710678118654752f));
}
DEV_INLINE float gelu_tanh(float x) {              // fast approx (bias path only)
  float x2 = x * x;
  float t  = x * fmaf(0.044715f, x2, 1.0f);
  float e  = __builtin_amdgcn_exp2f(2.3022082f * t);   // e^{2*0.79788456*t}
  return x * e * __frcp_rn(e + 1.0f);                  // x*tanh-form
}
DEV_INLINE f32x4 zero4() { f32x4 z; z[0]=0.f; z[1]=0.f; z[2]=0.f; z[3]=0.f; return z; }

// ---------------------------------------------------------------------------
// Weight cast + transpose: W[K][N] fp32 -> Wt[N][K] bf16 (per blockIdx.z layer)
// ---------------------------------------------------------------------------
__global__ __launch_bounds__(256) void k_cast_t(
    const float* __restrict__ W, unsigned short* __restrict__ Wt, int K, int N)
{
  __shared__ float s[64][68];
  const int tid = threadIdx.x;
  const size_t lay = (size_t)blockIdx.z * K * N;
  const int k0 = blockIdx.x * 64, n0 = blockIdx.y * 64;
  const int r = tid >> 4, c4 = (tid & 15) << 2;
  #pragma unroll
  for (int i = 0; i < 4; ++i)
    *(float4*)&s[r + i * 16][c4] =
        *(const float4*)(W + lay + (size_t)(k0 + r + i * 16) * N + n0 + c4);
  __syncthreads();
  const int n = tid & 63, kc = (tid >> 6) << 4;
  short8v v0, v1;
  #pragma unroll
  for (int j = 0; j < 8; ++j) v0[j] = (short)f2bf(s[kc + j][n]);
  #pragma unroll
  for (int j = 0; j < 8; ++j) v1[j] = (short)f2bf(s[kc + 8 + j][n]);
  unsigned short* dst = Wt + lay + (size_t)(n0 + n) * K + k0 + kc;
  *(short8v*)dst = v0;
  *(short8v*)(dst + 8) = v1;
}

// ---------------------------------------------------------------------------
// MFMA GEMM: C[2048][N] = A[2048][Kfull](bf16) @ Bt[N][Kfull]^T + bias
// BM=128, BK=64, BN in {64,128}. 4 waves (2x2). Double-buffered LDS,
// global_load_lds width-16, pre-swizzled source, ONE barrier per K-step:
// after barrier issue tile kt+1 into buf^1, compute tile kt from buf (m97).
// EPI: 0 bias->bf16 | 1 bias+gelu->bf16 | 3 raw fp32 split-K (z picks C0/C1,
//      bias only on z==0)
// ---------------------------------------------------------------------------
template<int BN, int EPI>
__global__ __launch_bounds__(256) void k_gemm(
    const unsigned short* __restrict__ A, const unsigned short* __restrict__ Bt,
    const float* __restrict__ bias,
    void* __restrict__ C0, void* __restrict__ C1, int N, int Kfull, int Klen)
{
  constexpr int NB = BN / 32;
  __shared__ __align__(16) unsigned short As[2][128 * 64];
  __shared__ __align__(16) unsigned short Bs[2][BN * 64];
  const int tid = threadIdx.x;
  const int l = tid & 63;
  const int w = tid >> 6, wr = w >> 1, wc = w & 1;
  const int row0 = blockIdx.x * 128, col0 = blockIdx.y * BN;
  const int z = blockIdx.z;
  const int Koff = z * Klen;
  const int NT = Klen >> 6;

  // staging: lane covers LDS row group + (l>>3), 16B slot (l&7); source chunk
  // pre-permuted by (l&7)^(l>>3) so swizzled reads recover logical data.
  const int lr = l >> 3;
  const int lc = ((l & 7) ^ lr) << 3;
  const unsigned short* gA[4];
  #pragma unroll
  for (int i = 0; i < 4; ++i)
    gA[i] = A + (size_t)(row0 + w * 32 + i * 8 + lr) * Kfull + Koff + lc;
  const unsigned short* gB[NB];
  #pragma unroll
  for (int i = 0; i < NB; ++i)
    gB[i] = Bt + (size_t)(col0 + w * 8 * NB + i * 8 + lr) * Kfull + Koff + lc;

  // prologue: tile 0 -> buf 0
  #pragma unroll
  for (int i = 0; i < 4; ++i) gload16(gA[i], &As[0][(w * 32 + i * 8) * 64]);
  #pragma unroll
  for (int i = 0; i < NB; ++i) gload16(gB[i], &Bs[0][(w * 8 * NB + i * 8) * 64]);

  f32x4 acc[4][NB];
  #pragma unroll
  for (int mi = 0; mi < 4; ++mi)
    #pragma unroll
    for (int ni = 0; ni < NB; ++ni) acc[mi][ni] = zero4();

  for (int kt = 0; kt < NT; ++kt) {
    const int cur = kt & 1;
    __syncthreads();            // tile kt resident (vmcnt drained), buf^1 free
    if (kt + 1 < NT) {          // prefetch stays in flight through the MFMAs
      #pragma unroll
      for (int i = 0; i < 4; ++i)
        gload16(gA[i] + (kt + 1) * 64, &As[cur ^ 1][(w * 32 + i * 8) * 64]);
      #pragma unroll
      for (int i = 0; i < NB; ++i)
        gload16(gB[i] + (kt + 1) * 64, &Bs[cur ^ 1][(w * 8 * NB + i * 8) * 64]);
    }
    #pragma unroll
    for (int kk = 0; kk < 2; ++kk) {
      short8v af[4], bf_[NB];
      #pragma unroll
      for (int mi = 0; mi < 4; ++mi) {
        int rw = wr * 64 + mi * 16 + (l & 15);
        int kb = (kk * 64 + ((l >> 4) << 4)) ^ ((rw & 7) << 4);
        af[mi] = *(const short8v*)&As[cur][rw * 64 + (kb >> 1)];
      }
      #pragma unroll
      for (int ni = 0; ni < NB; ++ni) {
        int rw = wc * (BN / 2) + ni * 16 + (l & 15);
        int kb = (kk * 64 + ((l >> 4) << 4)) ^ ((rw & 7) << 4);
        bf_[ni] = *(const short8v*)&Bs[cur][rw * 64 + (kb >> 1)];
      }
      #pragma unroll
      for (int mi = 0; mi < 4; ++mi)
        #pragma unroll
        for (int ni = 0; ni < NB; ++ni)
          acc[mi][ni] = __builtin_amdgcn_mfma_f32_16x16x32_bf16(
              af[mi], bf_[ni], acc[mi][ni], 0, 0, 0);
    }
  }

  // epilogue: C/D layout col=lane&15, row=(lane>>4)*4+reg
  const int cl = l & 15, rg = (l >> 4) << 2;
  void* Cv = (EPI == 3 && z) ? C1 : C0;
  float bv[NB];
  #pragma unroll
  for (int ni = 0; ni < NB; ++ni)
    bv[ni] = (EPI == 3 && z) ? 0.f : bias[col0 + wc * (BN / 2) + ni * 16 + cl];
  #pragma unroll
  for (int mi = 0; mi < 4; ++mi) {
    #pragma unroll
    for (int r = 0; r < 4; ++r) {
      size_t rowg = row0 + wr * 64 + mi * 16 + rg + r;
      #pragma unroll
      for (int ni = 0; ni < NB; ++ni) {
        size_t off = rowg * N + col0 + wc * (BN / 2) + ni * 16 + cl;
        float v = acc[mi][ni][r] + bv[ni];
        if (EPI == 0) ((unsigned short*)Cv)[off] = f2bf(v);
        if (EPI == 1) ((unsigned short*)Cv)[off] = f2bf(gelu_f(v));
        if (EPI == 3) ((float*)Cv)[off] = v;
      }
    }
  }
}

// ---------------------------------------------------------------------------
// Gaussian edge features + MLP via MFMA. 64 positions/block. tanh-gelu,
// folded gaussian constants, float4-packed params.
// ---------------------------------------------------------------------------
__global__ __launch_bounds__(256) void k_gauss(
    const float* __restrict__ dist, const int* __restrict__ edge,
    const float* __restrict__ gmul, const float* __restrict__ gbias,
    const float* __restrict__ gmeans, const float* __restrict__ gstds,
    const unsigned short* __restrict__ gp1wt, const float* __restrict__ gp1b,
    const float* __restrict__ gp2w, const float* __restrict__ gp2b,
    float* __restrict__ bias_out)
{
  __shared__ float4 prm[128];   // mean, c2=-log2e/2*inv^2, coef, b1
  __shared__ float b2s[8];
  __shared__ __align__(16) unsigned short w2t[16 * 136];
  __shared__ __align__(16) unsigned short t1[4][2048];  // per-wave 16x128 bf16
  const int tid = threadIdx.x, l = tid & 63, w = tid >> 6;
  const int pos0 = blockIdx.x * 64;

  if (tid < 128) {
    float sd = fabsf(gstds[tid]) + 1e-5f;
    float inv = 1.0f / sd;
    prm[tid] = make_float4(gmeans[tid], -0.72134752f * inv * inv,
                           0.39894268f * inv, gp1b[tid]);
  }
  if (tid < 8) b2s[tid] = gp2b[tid];
  for (int i = tid; i < 2048; i += 256) {
    int hh = i & 15, k = i >> 4;
    w2t[hh * 136 + k] = (hh < 8) ? f2bf(gp2w[k * 8 + hh]) : (unsigned short)0;
  }
  __syncthreads();   // the only barrier

  const int p = pos0 + w * 16 + (l & 15);
  const int et = edge[p];
  const float y = gmul[et] * dist[p] + gbias[et];

  // phase A: gaussians straight into A-fragments
  short8v ga[4];
  #pragma unroll
  for (int ks = 0; ks < 4; ++ks) {
    #pragma unroll
    for (int j = 0; j < 8; ++j) {
      int k = ks * 32 + ((l >> 4) << 3) + j;
      float4 pk = prm[k];
      float d = y - pk.x;
      ga[ks][j] = (short)f2bf_hw(__builtin_amdgcn_exp2f(pk.y * d * d) * pk.z);
    }
  }
  // phase B: t = g @ gp1w (B-frags from L2-hot gp1wt)
  f32x4 acc[8];
  #pragma unroll
  for (int n = 0; n < 8; ++n) {
    acc[n] = zero4();
    const unsigned short* bp = gp1wt + (size_t)(n * 16 + (l & 15)) * 128 + ((l >> 4) << 3);
    #pragma unroll
    for (int ks = 0; ks < 4; ++ks)
      acc[n] = __builtin_amdgcn_mfma_f32_16x16x32_bf16(
          ga[ks], *(const short8v*)(bp + ks * 32), acc[n], 0, 0, 0);
  }
  // tanh-gelu -> per-wave t1 (windowed swizzle, conflict-free)
  unsigned short* tw = t1[w];
  {
    const int rb = (l >> 4) << 2;
    #pragma unroll
    for (int n = 0; n < 8; ++n) {
      int col2 = (n * 16 + (l & 15)) * 2;
      float bb = prm[n * 16 + (l & 15)].w;
      #pragma unroll
      for (int r = 0; r < 4; ++r) {
        int row = rb + r;
        int swz = ((row & 3) << 4) ^ ((row >> 2) << 5);
        tw[(row * 256 + (col2 ^ swz)) >> 1] = f2bf_hw(gelu_tanh(acc[n][r] + bb));
      }
    }
  }
  // phase C: pb = t1 @ gp2w (same-wave LDS dep, no barrier)
  f32x4 o4 = zero4();
  {
    const int row = l & 15;
    const int swz = ((row & 3) << 4) ^ ((row >> 2) << 5);
    #pragma unroll
    for (int ks = 0; ks < 4; ++ks) {
      short8v af = *(const short8v*)&tw[(row * 256 + ((ks * 64 + ((l >> 4) << 4)) ^ swz)) >> 1];
      short8v bf_ = *(const short8v*)&w2t[(l & 15) * 136 + ks * 32 + ((l >> 4) << 3)];
      o4 = __builtin_amdgcn_mfma_f32_16x16x32_bf16(af, bf_, o4, 0, 0, 0);
    }
  }
  const int hh = l & 15;
  if (hh < 8) {
    int b = pos0 >> 16;
    int ij = (pos0 & 65535) + w * 16 + ((l >> 4) << 2);
    float4 vv;
    vv.x = o4[0] + b2s[hh]; vv.y = o4[1] + b2s[hh];
    vv.z = o4[2] + b2s[hh]; vv.w = o4[3] + b2s[hh];
    *(float4*)(bias_out + ((size_t)((b << 3) + hh) << 16) + ij) = vv;
  }
}

// ---------------------------------------------------------------------------
// Embedding gather + LayerNorm -> fp32 x
// ---------------------------------------------------------------------------
__global__ __launch_bounds__(256) void k_embed_ln(
    const float* __restrict__ emb, const int* __restrict__ tokens,
    const float* __restrict__ g, const float* __restrict__ bp,
    float* __restrict__ out)
{
  __shared__ float red[4], red2[4];
  const int t = threadIdx.x;
  const int row = blockIdx.x;
  const float* xr = emb + (size_t)tokens[row] * 768;
  float v0 = xr[t], v1 = xr[t + 256], v2 = xr[t + 512];
  float s = v0 + v1 + v2;
  #pragma unroll
  for (int o = 32; o; o >>= 1) s += __shfl_down(s, o);
  if ((t & 63) == 0) red[t >> 6] = s;
  __syncthreads();
  float mean = (red[0] + red[1] + red[2] + red[3]) * (1.0f / 768.0f);
  float d0 = v0 - mean, d1 = v1 - mean, d2 = v2 - mean;
  float q = d0 * d0 + d1 * d1 + d2 * d2;
  #pragma unroll
  for (int o = 32; o; o >>= 1) q += __shfl_down(q, o);
  if ((t & 63) == 0) red2[t >> 6] = q;
  __syncthreads();
  float rstd = rsqrtf((red2[0] + red2[1] + red2[2] + red2[3]) * (1.0f / 768.0f) + 1e-3f);
  float* outr = out + (size_t)row * 768;
  outr[t]       = d0 * rstd * g[t]       + bp[t];
  outr[t + 256] = d1 * rstd * g[t + 256] + bp[t + 256];
  outr[t + 512] = d2 * rstd * g[t + 512] + bp[t + 512];
}

// LayerNorm fp32 -> bf16 h
__global__ __launch_bounds__(256) void k_ln_bf(
    const float* __restrict__ in, const float* __restrict__ g,
    const float* __restrict__ bp, unsigned short* __restrict__ out)
{
  __shared__ float red[4], red2[4];
  const int t = threadIdx.x;
  const size_t base = (size_t)blockIdx.x * 768;
  const float* xr = in + base;
  float v0 = xr[t], v1 = xr[t + 256], v2 = xr[t + 512];
  float s = v0 + v1 + v2;
  #pragma unroll
  for (int o = 32; o; o >>= 1) s += __shfl_down(s, o);
  if ((t & 63) == 0) red[t >> 6] = s;
  __syncthreads();
  float mean = (red[0] + red[1] + red[2] + red[3]) * (1.0f / 768.0f);
  float d0 = v0 - mean, d1 = v1 - mean, d2 = v2 - mean;
  float q = d0 * d0 + d1 * d1 + d2 * d2;
  #pragma unroll
  for (int o = 32; o; o >>= 1) q += __shfl_down(q, o);
  if ((t & 63) == 0) red2[t >> 6] = q;
  __syncthreads();
  float rstd = rsqrtf((red2[0] + red2[1] + red2[2] + red2[3]) * (1.0f / 768.0f) + 1e-3f);
  unsigned short* outr = out + base;
  outr[t]       = f2bf(d0 * rstd * g[t]       + bp[t]);
  outr[t + 256] = f2bf(d1 * rstd * g[t + 256] + bp[t + 256]);
  outr[t + 512] = f2bf(d2 * rstd * g[t + 512] + bp[t + 512]);
}

// ---------------------------------------------------------------------------
// k_fuse: x = p0 + p1 + x (split-K combine + residual); optional LN -> h bf16
// ---------------------------------------------------------------------------
template<int DO_LN>
__global__ __launch_bounds__(256) void k_fuse(
    const float* __restrict__ p0, const float* __restrict__ p1,
    const float* __restrict__ g, const float* __restrict__ bp,
    float* __restrict__ x, unsigned short* __restrict__ h)
{
  __shared__ float red[4], red2[4];
  const int t = threadIdx.x;
  const size_t base = (size_t)blockIdx.x * 768;
  float v0 = p0[base + t]       + p1[base + t]       + x[base + t];
  float v1 = p0[base + t + 256] + p1[base + t + 256] + x[base + t + 256];
  float v2 = p0[base + t + 512] + p1[base + t + 512] + x[base + t + 512];
  x[base + t]       = v0;
  x[base + t + 256] = v1;
  x[base + t + 512] = v2;
  if (DO_LN) {
    float s = v0 + v1 + v2;
    #pragma unroll
    for (int o = 32; o; o >>= 1) s += __shfl_down(s, o);
    if ((t & 63) == 0) red[t >> 6] = s;
    __syncthreads();
    float mean = (red[0] + red[1] + red[2] + red[3]) * (1.0f / 768.0f);
    float d0 = v0 - mean, d1 = v1 - mean, d2 = v2 - mean;
    float q = d0 * d0 + d1 * d1 + d2 * d2;
    #pragma unroll
    for (int o = 32; o; o >>= 1) q += __shfl_down(q, o);
    if ((t & 63) == 0) red2[t >> 6] = q;
    __syncthreads();
    float rstd = rsqrtf((red2[0] + red2[1] + red2[2] + red2[3]) * (1.0f / 768.0f) + 1e-3f);
    h[base + t]       = f2bf(d0 * rstd * g[t]       + bp[t]);
    h[base + t + 256] = f2bf(d1 * rstd * g[t + 256] + bp[t + 256]);
    h[base + t + 512] = f2bf(d2 * rstd * g[t + 512] + bp[t + 512]);
  }
}

// ---------------------------------------------------------------------------
// V transpose: P[b][tok][h*96+d] -> Vt[bh][d][tok]  (bf16)
// ---------------------------------------------------------------------------
__global__ __launch_bounds__(256) void k_transV(
    const unsigned short* __restrict__ P, unsigned short* __restrict__ Vt)
{
  __shared__ unsigned short s[64 * 100];
  const int tid = threadIdx.x;
  const int i0 = blockIdx.x * 64, bh = blockIdx.y, b = bh >> 3, h = bh & 7;
  const unsigned short* Pb = P + ((size_t)b * 256 + i0) * 768 + h * 96;
  #pragma unroll
  for (int i = 0; i < 6; ++i) {
    int o = (tid + i * 256) * 8;
    int row = o / 192, c = o - row * 192;
    *(short4v*)&s[row * 100 + (c >> 1)] =
        *(const short4v*)(Pb + (size_t)row * 768 + (c >> 1));
  }
  __syncthreads();
  #pragma unroll
  for (int i = 0; i < 3; ++i) {
    int u = tid + i * 256;
    int d = u >> 3, tk = (u & 7) << 3;
    short8v v;
    #pragma unroll
    for (int j = 0; j < 8; ++j) v[j] = (short)s[(tk + j) * 100 + d];
    *(short8v*)(Vt + ((size_t)bh * 96 + d) * 256 + i0 + tk) = v;
  }
}

// ---------------------------------------------------------------------------
// Fused attention: probs = softmax(scale*Q.K^T + bias); O = probs @ V.
// K/V fragments from L2-hot global; probs in per-wave LDS; zero barriers.
// ---------------------------------------------------------------------------
__global__ __launch_bounds__(256) void k_attn(
    const unsigned short* __restrict__ P, const unsigned short* __restrict__ Vt,
    const float* __restrict__ bias, unsigned short* __restrict__ O)
{
  __shared__ __align__(16) unsigned short pl[4][4096];  // per-wave 16x256 bf16
  const int tid = threadIdx.x, l = tid & 63, w = tid >> 6;
  const int i0 = blockIdx.x << 6, bh = blockIdx.y, b = bh >> 3, hh = bh & 7;
  const unsigned short* Pb = P + (size_t)b * 196608 + hh * 96;

  short8v aq[3];
  const int rq = i0 + w * 16 + (l & 15);
  #pragma unroll
  for (int ks = 0; ks < 3; ++ks)
    aq[ks] = *(const short8v*)(Pb + (size_t)rq * 768 + ks * 32 + ((l >> 4) << 3));

  f32x4 acc[16];
  #pragma unroll
  for (int n = 0; n < 16; ++n) {
    acc[n] = zero4();
    const unsigned short* kp = Pb + (size_t)(n * 16 + (l & 15)) * 768 + ((l >> 4) << 3);
    #pragma unroll
    for (int ks = 0; ks < 3; ++ks)
      acc[n] = __builtin_amdgcn_mfma_f32_16x16x32_bf16(
          aq[ks], *(const short8v*)(kp + ks * 32), acc[n], 0, 0, 0);
  }

  const float scale = 0.10206207261596577f;  // 1/sqrt(96)
  float inv[4];
  unsigned short* plw = pl[w];
  const size_t brow = ((size_t)bh * 256 + i0 + w * 16 + ((l >> 4) << 2)) * 256 + (l & 15);
  #pragma unroll
  for (int r = 0; r < 4; ++r) {
    const float* bptr = bias + brow + (size_t)r * 256;
    float m = -1e30f;
    #pragma unroll
    for (int n = 0; n < 16; ++n) {
      float v = acc[n][r] * scale + bptr[n * 16];
      acc[n][r] = v;
      m = fmaxf(m, v);
    }
    m = fmaxf(m, __shfl_xor(m, 1)); m = fmaxf(m, __shfl_xor(m, 2));
    m = fmaxf(m, __shfl_xor(m, 4)); m = fmaxf(m, __shfl_xor(m, 8));
    const int rowL = ((l >> 4) << 2) + r;
    const int swz = ((rowL & 3) << 4) ^ ((rowL >> 2) << 5);
    const int cb = (l & 15) << 1;
    float s = 0.f;
    #pragma unroll
    for (int n = 0; n < 16; ++n) {
      float e = __expf(acc[n][r] - m);
      s += e;
      plw[(rowL * 512 + ((cb + (n << 5)) ^ swz)) >> 1] = f2bf_hw(e);
    }
    s += __shfl_xor(s, 1); s += __shfl_xor(s, 2);
    s += __shfl_xor(s, 4); s += __shfl_xor(s, 8);
    inv[r] = 1.0f / s;
  }

  const int rowA = l & 15;
  const int swzA = ((rowA & 3) << 4) ^ ((rowA >> 2) << 5);
  short8v pa[8];
  #pragma unroll
  for (int ks = 0; ks < 8; ++ks)
    pa[ks] = *(const short8v*)&plw[(rowA * 512 + ((ks * 64 + ((l >> 4) << 4)) ^ swzA)) >> 1];

  unsigned short* Ob = O + ((size_t)b * 256 + i0 + w * 16 + ((l >> 4) << 2)) * 768
                       + hh * 96 + (l & 15);
  #pragma unroll
  for (int n = 0; n < 6; ++n) {
    f32x4 a2 = zero4();
    const unsigned short* vb = Vt + ((size_t)bh * 96 + n * 16 + (l & 15)) * 256 + ((l >> 4) << 3);
    #pragma unroll
    for (int ks = 0; ks < 8; ++ks)
      a2 = __builtin_amdgcn_mfma_f32_16x16x32_bf16(
          pa[ks], *(const short8v*)(vb + ks * 32), a2, 0, 0, 0);
    #pragma unroll
    for (int r = 0; r < 4; ++r)
      Ob[(size_t)r * 768 + n * 16] = f2bf(a2[r] * inv[r]);
  }
}

// ---------------------------------------------------------------------------
// Final LN (row 0 of each batch) + classifier head -> out (8,2), fp32
// ---------------------------------------------------------------------------
__global__ __launch_bounds__(256) void k_cls(
    const float* __restrict__ x, const float* __restrict__ fg,
    const float* __restrict__ fb, const float* __restrict__ w1,
    const float* __restrict__ b1, const float* __restrict__ w2,
    const float* __restrict__ b2, float* __restrict__ out)
{
  __shared__ float ln[768];
  __shared__ float t1[768];
  __shared__ float red[8];
  __shared__ float r2[8];
  const int t = threadIdx.x;
  const int b = blockIdx.x;
  const float* xr = x + (size_t)b * 256 * 768;
  float v0 = xr[t], v1 = xr[t + 256], v2 = xr[t + 512];
  float s = v0 + v1 + v2;
  #pragma unroll
  for (int o = 32; o; o >>= 1) s += __shfl_down(s, o);
  if ((t & 63) == 0) red[t >> 6] = s;
  __syncthreads();
  float mean = (red[0] + red[1] + red[2] + red[3]) * (1.0f / 768.0f);
  float d0 = v0 - mean, d1 = v1 - mean, d2 = v2 - mean;
  float q = d0 * d0 + d1 * d1 + d2 * d2;
  #pragma unroll
  for (int o = 32; o; o >>= 1) q += __shfl_down(q, o);
  if ((t & 63) == 0) red[4 + (t >> 6)] = q;
  __syncthreads();
  float rstd = rsqrtf((red[4] + red[5] + red[6] + red[7]) * (1.0f / 768.0f) + 1e-3f);
  ln[t]       = d0 * rstd * fg[t]       + fb[t];
  ln[t + 256] = d1 * rstd * fg[t + 256] + fb[t + 256];
  ln[t + 512] = d2 * rstd * fg[t + 512] + fb[t + 512];
  __syncthreads();
  float a0 = b1[t], a1 = b1[t + 256], a2 = b1[t + 512];
  for (int d = 0; d < 768; ++d) {
    float lv = ln[d];
    a0 = fmaf(lv, w1[d * 768 + t], a0);
    a1 = fmaf(lv, w1[d * 768 + t + 256], a1);
    a2 = fmaf(lv, w1[d * 768 + t + 512], a2);
  }
  t1[t]       = gelu_f(a0);
  t1[t + 256] = gelu_f(a1);
  t1[t + 512] = gelu_f(a2);
  __syncthreads();
  float p0 = 0.f, p1 = 0.f;
  #pragma unroll
  for (int oo = 0; oo < 3; ++oo) {
    int d = t + oo * 256;
    p0 = fmaf(t1[d], w2[d * 2], p0);
    p1 = fmaf(t1[d], w2[d * 2 + 1], p1);
  }
  #pragma unroll
  for (int o = 32; o; o >>= 1) {
    p0 += __shfl_down(p0, o);
    p1 += __shfl_down(p1, o);
  }
  if ((t & 63) == 0) { r2[t >> 6] = p0; r2[4 + (t >> 6)] = p1; }
  __syncthreads();
  if (t == 0) {
    out[b * 2]     = r2[0] + r2[1] + r2[2] + r2[3] + b2[0];
    out[b * 2 + 1] = r2[4] + r2[5] + r2[6] + r2[7] + b2[1];
  }
}

// ---------------------------------------------------------------------------
extern "C" void kernel_launch(void* const* d_in, const int* in_sizes, int n_in,
                              void* d_out, int out_size, void* d_ws, size_t ws_size,
                              hipStream_t stream)
{
  const float* dist    = (const float*)d_in[0];
  const float* tok_emb = (const float*)d_in[1];
  const float* gmeans  = (const float*)d_in[2];
  const float* gstds   = (const float*)d_in[3];
  const float* gmul    = (const float*)d_in[4];
  const float* gbias   = (const float*)d_in[5];
  const float* gp1w    = (const float*)d_in[6];
  const float* gp1b    = (const float*)d_in[7];
  const float* gp2w    = (const float*)d_in[8];
  const float* gp2b    = (const float*)d_in[9];
  const float* embg    = (const float*)d_in[10];
  const float* embb    = (const float*)d_in[11];
  const float* Wq      = (const float*)d_in[12];
  const float* bq      = (const float*)d_in[13];
  const float* Wo      = (const float*)d_in[14];
  const float* bo      = (const float*)d_in[15];
  const float* ln1g    = (const float*)d_in[16];
  const float* ln1b    = (const float*)d_in[17];
  const float* W1      = (const float*)d_in[18];
  const float* b1      = (const float*)d_in[19];
  const float* W2      = (const float*)d_in[20];
  const float* b2      = (const float*)d_in[21];
  const float* ln2g    = (const float*)d_in[22];
  const float* ln2b    = (const float*)d_in[23];
  const float* fing    = (const float*)d_in[24];
  const float* finb    = (const float*)d_in[25];
  const float* cw1     = (const float*)d_in[26];
  const float* cb1     = (const float*)d_in[27];
  const float* cw2     = (const float*)d_in[28];
  const float* cb2     = (const float*)d_in[29];
  const int*   tokens  = (const int*)d_in[30];
  const int*   edge    = (const int*)d_in[31];

  // workspace layout
  float* ws   = (float*)d_ws;
  float* bias = ws;                        // 4,194,304 f32
  float* x    = bias + 4194304;            // 1,572,864 f32
  float* p0   = x + 1572864;               // 1,572,864 f32
  float* p1   = p0 + 1572864;              // 1,572,864 f32
  unsigned short* hO  = (unsigned short*)(p1 + 1572864);  // 1,572,864 bf16
  unsigned short* P   = hO + 1572864;                     // 1,572,864 bf16
  unsigned short* Vt  = P + 1572864;                      // 1,572,864 bf16
  unsigned short* f1  = Vt + 1572864;                     // 6,291,456 bf16
  unsigned short* Wqt = f1 + 6291456;                     // 4,718,592 bf16
  unsigned short* Wot = Wqt + 4718592;                    // 4,718,592 bf16
  unsigned short* W1t = Wot + 4718592;                    // 18,874,368 bf16
  unsigned short* W2t = W1t + 18874368;                   // 18,874,368 bf16
  unsigned short* g1t = W2t + 18874368;                   // 16,384 bf16
  // total ~152 MiB

  k_cast_t<<<dim3(12, 12, 8), 256, 0, stream>>>(Wq, Wqt, 768, 768);
  k_cast_t<<<dim3(12, 12, 8), 256, 0, stream>>>(Wo, Wot, 768, 768);
  k_cast_t<<<dim3(12, 48, 8), 256, 0, stream>>>(W1, W1t, 768, 3072);
  k_cast_t<<<dim3(48, 12, 8), 256, 0, stream>>>(W2, W2t, 3072, 768);
  k_cast_t<<<dim3(2, 2, 1), 256, 0, stream>>>(gp1w, g1t, 128, 128);

  k_gauss<<<8192, 256, 0, stream>>>(dist, edge, gmul, gbias, gmeans, gstds,
                                    g1t, gp1b, gp2w, gp2b, bias);
  k_embed_ln<<<2048, 256, 0, stream>>>(tok_emb, tokens, embg, embb, x);
  k_ln_bf<<<2048, 256, 0, stream>>>(x, ln1g, ln1b, hO);

  for (int l = 0; l < 8; ++l) {
    k_gemm<64, 0><<<dim3(16, 12, 1), 256, 0, stream>>>(
        hO, Wqt + (size_t)l * 589824, bq + l * 768, P, nullptr, 768, 768, 768);
    k_transV<<<dim3(4, 64), 256, 0, stream>>>(P, Vt);
    k_attn<<<dim3(4, 64), 256, 0, stream>>>(P, Vt, bias, hO);
    k_gemm<64, 3><<<dim3(16, 12, 2), 256, 0, stream>>>(
        hO, Wot + (size_t)l * 589824, bo + l * 768, p0, p1, 768, 768, 384);
    k_fuse<1><<<2048, 256, 0, stream>>>(p0, p1, ln2g + l * 768, ln2b + l * 768, x, hO);
    k_gemm<128, 1><<<dim3(16, 24, 1), 256, 0, stream>>>(
        hO, W1t + (size_t)l * 2359296, b1 + l * 3072, f1, nullptr, 3072, 768, 768);
    k_gemm<64, 3><<<dim3(16, 12, 2), 256, 0, stream>>>(
        f1, W2t + (size_t)l * 2359296, b2 + l * 768, p0, p1, 768, 3072, 1536);
    if (l < 7)
      k_fuse<1><<<2048, 256, 0, stream>>>(p0, p1, ln1g + (l + 1) * 768,
                                          ln1b + (l + 1) * 768, x, hO);
    else
      k_fuse<0><<<2048, 256, 0, stream>>>(p0, p1, nullptr, nullptr, x, hO);
  }
  k_cls<<<8, 256, 0, stream>>>(x, fing, finb, cw1, cb1, cw2, cb2, (float*)d_out);
}